// Round 6
// baseline (115.144 us; speedup 1.0000x reference)
//
#include <hip/hip_runtime.h>
#include <hip/hip_bf16.h>
#include <math.h>

#define H_    12
#define B_    2
#define N_    512
#define BH_   (B_*H_)
#define QSCALE 0.14433756729740643f          // 1/sqrt(48)
#define CPT_K  0.13608276348795434f          // sqrt(1/54)

// ---------------- ws layout (float units) ----------------
#define OFF_WPP  1245184                     // bf16 Wproj-pack [18nt][4ks][4kq][64n][8]
#define OFF_WOP  1318912                     // bf16 Wout-pack  [2nt][18ks][4kq][64n][8]
#define OFF_BIA  1355776                     // f32 fused bias [1152]
#define OFF_QB   1356928                     // bf16 [bh][512][32]
#define OFF_KP   1553536                     // bf16 [bh][32jt][4kq][16j][8]
#define OFF_VP   1750144                     // bf16 [bh][16jt32][3nq][4kq][16n][8j]
#define OFF_SA   2045056                     // f32 [bh*512]
#define OFF_SB   2057344                     // f32 [bh*512]
#define OFF_CATP 2069632                     // bf16 [64mt][18ks][4kq][16m][8]

typedef __attribute__((ext_vector_type(8))) short sh8;
typedef __attribute__((ext_vector_type(4))) float f32x4;
typedef unsigned short u16t;

static __device__ __forceinline__ u16t f2b(float x) {
    __hip_bfloat16 h = __float2bfloat16(x);
    return *reinterpret_cast<u16t*>(&h);
}
static __device__ __forceinline__ int catp_idx(int tok, int col) {
    return (tok >> 4)*9216 + (col >> 5)*512 + ((col >> 3) & 3)*128
         + (tok & 15)*8 + (col & 7);
}

// ---------------------------------------------------------------------------
// Kernel 0: pack Wproj, Wout into MFMA-fragment bf16 images + fused bias.
// sh8 task ranges: [0,18432) Wproj, [18432,27648) Wout, [27648,28800) bias.
// ---------------------------------------------------------------------------
__global__ __launch_bounds__(256) void convert_kernel(
    const float* __restrict__ Wq,  const float* __restrict__ bq,
    const float* __restrict__ Wkv, const float* __restrict__ bkv,
    const float* __restrict__ Wqp, const float* __restrict__ bqp,
    const float* __restrict__ Wkvp,const float* __restrict__ bkvp,
    const float* __restrict__ Wout, float* __restrict__ ws)
{
    const int g = blockIdx.x * 256 + threadIdx.x;
    union { sh8 v; u16t u[8]; } pk;

    if (g < 18432) {                       // Wproj-packed
        int u = g;
        int n = u & 63, kq = (u >> 6) & 3, ks = (u >> 8) & 3, nt = u >> 10;
        int col = nt*64 + n, k0 = ks*32 + kq*8;
        const float* w; int lc, od;
        if (col < 192)      { w = Wq;   lc = col;     od = 192; }
        else if (col < 576) { w = Wkv;  lc = col-192; od = 384; }
        else if (col < 720) { w = Wqp;  lc = col-576; od = 144; }
        else                { w = Wkvp; lc = col-720; od = 432; }
        #pragma unroll
        for (int j = 0; j < 8; ++j) pk.u[j] = f2b(w[(k0+j)*od + lc]);
        *((sh8*)((u16t*)(ws + OFF_WPP)) + u) = pk.v;
    } else if (g < 27648) {                // Wout-packed (9216 frags)
        int u = g - 18432;
        int n = u & 63, kq = (u >> 6) & 3, rem = u >> 8;   // rem in [0,36)
        int ks = rem % 18, nt = rem / 18;
        int col = nt*64 + n, k0 = ks*32 + kq*8;
        #pragma unroll
        for (int j = 0; j < 8; ++j) pk.u[j] = f2b(Wout[(k0+j)*128 + col]);
        *((sh8*)((u16t*)(ws + OFF_WOP)) + u) = pk.v;
    } else if (g < 28800) {                // fused bias
        int col = g - 27648;
        float bv;
        if (col < 192)      bv = bq[col];
        else if (col < 576) bv = bkv[col-192];
        else if (col < 720) bv = bqp[col-576];
        else                bv = bkvp[col-720];
        ws[OFF_BIA + col] = bv;
    }
}

// ---------------------------------------------------------------------------
// Kernel 1: fused proj GEMM + rotation + bf16 pack. Block = 16 tokens,
// 4 waves; wave w computes col-groups [w*18, w*18+18) (16 cols each) with
// in-register f32->bf16 A-frags. Result -> LDS, rotate points in-place,
// then pack Qb/Kp/Vp/sa/sb exactly as the verified pack_kernel did.
// ---------------------------------------------------------------------------
__global__ __launch_bounds__(256) void projpack_kernel(
    const float* __restrict__ s,
    const float* __restrict__ Rg, const float* __restrict__ tg,
    const float* __restrict__ hwg, float* __restrict__ ws)
{
    __shared__ float ldsP[16][1160];   // 16 tokens x 1152 (+8 pad)

    u16t* Qb = (u16t*)(ws + OFF_QB);
    u16t* Kp = (u16t*)(ws + OFF_KP);
    u16t* Vp = (u16t*)(ws + OFF_VP);
    float* sa_g = ws + OFF_SA;
    float* sb_g = ws + OFF_SB;

    const int tid  = threadIdx.x;
    const int w    = tid >> 6, lane = tid & 63;
    const int kq   = lane >> 4, lx = lane & 15;
    const int tok0 = blockIdx.x * 16;
    const int b    = tok0 >> 9, n0 = tok0 & 511;

    // A-frags: s rows tok0+lx, k = ks*32 + kq*8 .. +8, converted in-register
    sh8 afr[4];
    #pragma unroll
    for (int ks = 0; ks < 4; ++ks) {
        const float* src = s + (tok0+lx)*128 + ks*32 + kq*8;
        float4 u0 = *(const float4*)(src);
        float4 u1 = *(const float4*)(src+4);
        union { sh8 v; u16t u[8]; } pk;
        pk.u[0]=f2b(u0.x); pk.u[1]=f2b(u0.y); pk.u[2]=f2b(u0.z); pk.u[3]=f2b(u0.w);
        pk.u[4]=f2b(u1.x); pk.u[5]=f2b(u1.y); pk.u[6]=f2b(u1.z); pk.u[7]=f2b(u1.w);
        afr[ks] = pk.v;
    }

    const sh8* Bp = (const sh8*)((const u16t*)(ws + OFF_WPP));
    const float* bias = ws + OFF_BIA;

    #pragma unroll 2
    for (int g = 0; g < 18; ++g) {
        int gg = w*18 + g;                 // col-group 0..71
        int nt = gg >> 2, nq = gg & 3;
        f32x4 acc = {0.f,0.f,0.f,0.f};
        #pragma unroll
        for (int ks = 0; ks < 4; ++ks) {
            sh8 bf = Bp[((nt*4 + ks)*4 + kq)*64 + nq*16 + lx];
            acc = __builtin_amdgcn_mfma_f32_16x16x32_bf16(afr[ks], bf, acc, 0, 0, 0);
        }
        float bv = bias[gg*16 + lx];
        #pragma unroll
        for (int r = 0; r < 4; ++r)
            ldsP[kq*4 + r][gg*16 + lx] = acc[r] + bv;
    }
    __syncthreads();

    // in-place rotation: qp (cols 576..720, x/y/z at p, 48+p, 96+p)
    for (int idx = tid; idx < 16*48; idx += 256) {
        int tk = idx / 48, p = idx % 48;
        int tok = tok0 + tk;
        const float* Rr = Rg + tok*9;
        const float* tr = tg + tok*3;
        float x0 = ldsP[tk][576 +  0 + p];
        float x1 = ldsP[tk][576 + 48 + p];
        float x2 = ldsP[tk][576 + 96 + p];
        ldsP[tk][576 +  0 + p] = Rr[0]*x0 + Rr[1]*x1 + Rr[2]*x2 + tr[0];
        ldsP[tk][576 + 48 + p] = Rr[3]*x0 + Rr[4]*x1 + Rr[5]*x2 + tr[1];
        ldsP[tk][576 + 96 + p] = Rr[6]*x0 + Rr[7]*x1 + Rr[8]*x2 + tr[2];
    }
    // in-place rotation: kvp (cols 720..1152, x/y/z at p, 144+p, 288+p)
    for (int idx = tid; idx < 16*144; idx += 256) {
        int tk = idx / 144, p = idx % 144;
        int tok = tok0 + tk;
        const float* Rr = Rg + tok*9;
        const float* tr = tg + tok*3;
        float x0 = ldsP[tk][720 +   0 + p];
        float x1 = ldsP[tk][720 + 144 + p];
        float x2 = ldsP[tk][720 + 288 + p];
        ldsP[tk][720 +   0 + p] = Rr[0]*x0 + Rr[1]*x1 + Rr[2]*x2 + tr[0];
        ldsP[tk][720 + 144 + p] = Rr[3]*x0 + Rr[4]*x1 + Rr[5]*x2 + tr[1];
        ldsP[tk][720 + 288 + p] = Rr[6]*x0 + Rr[7]*x1 + Rr[8]*x2 + tr[2];
    }
    __syncthreads();

    // Qb rows : tasks (tk,h,half)
    for (int idx = tid; idx < 16*24; idx += 256) {
        int tk = idx / 24, r2 = idx % 24, h = r2 >> 1, half = r2 & 1;
        float hx = hwg[h];
        float sp = (hx > 20.f) ? hx : log1pf(__expf(hx));
        float c_pt = -0.5f * sp * CPT_K;
        union { sh8 v[2]; u16t u[16]; } pk;
        if (half == 0) {
            #pragma unroll
            for (int e = 0; e < 16; ++e) pk.u[e] = f2b(ldsP[tk][h*16 + e] * QSCALE);
        } else {
            float qs = -2.f * c_pt;
            #pragma unroll
            for (int e = 0; e < 12; ++e)
                pk.u[e] = f2b(ldsP[tk][576 + (e%3)*48 + h*4 + e/3] * qs);
            pk.u[12]=0; pk.u[13]=0; pk.u[14]=0; pk.u[15]=0;
        }
        u16t* dst = Qb + ((b*H_+h)*N_ + n0 + tk)*32 + half*16;
        *(sh8*)dst = pk.v[0];
        *(sh8*)(dst+8) = pk.v[1];
    }
    // Kp: frag-packed [bh][jt16][kq][j16][8] : tasks (tk,h,kq)
    for (int idx = tid; idx < 16*48; idx += 256) {
        int tk = idx / 48, r2 = idx % 48, h = r2 >> 2, fq = r2 & 3;
        int j = n0 + tk, bh = b*H_ + h;
        union { sh8 v; u16t u[8]; } pk;
        #pragma unroll
        for (int e = 0; e < 8; ++e) {
            int c = fq*8 + e;
            float val;
            if (c < 16)      val = ldsP[tk][192 + h*32 + c];
            else if (c < 28) val = ldsP[tk][720 + ((c-16)%3)*144 + h*12 + (c-16)/3];
            else             val = 0.f;
            pk.u[e] = f2b(val);
        }
        *(sh8*)(Kp + bh*16384 + (j>>4)*512 + fq*128 + (j&15)*8) = pk.v;
    }
    // Vp: frag-packed, 16B stores along j: tasks (h,d,grp)
    for (int idx = tid; idx < 960; idx += 256) {
        int h = idx / 80, r2 = idx % 80, d = r2 >> 1, grp = r2 & 1;
        int bh = b*H_ + h;
        union { sh8 v; u16t u[8]; } pk;
        #pragma unroll
        for (int e = 0; e < 8; ++e) {
            int tk = grp*8 + e;
            float val;
            if (d < 16) val = ldsP[tk][192 + h*32 + 16 + d];
            else        val = ldsP[tk][720 + ((d-16)%3)*144 + h*12 + 4 + (d-16)/3];
            pk.u[e] = f2b(val);
        }
        int j = n0 + grp*8;
        *(sh8*)(Vp + bh*24576 + (j>>5)*1536 + (d>>4)*512 + ((j>>3)&3)*128
                + (d&15)*8) = pk.v;
    }
    // sa/sb : tasks (tk,h)
    for (int idx = tid; idx < 16*12; idx += 256) {
        int tk = idx / 12, h = idx % 12;
        float hx = hwg[h];
        float sp = (hx > 20.f) ? hx : log1pf(__expf(hx));
        float c_pt = -0.5f * sp * CPT_K;
        float sq = 0.f, sk = 0.f;
        #pragma unroll
        for (int pp = 0; pp < 4; ++pp)
            #pragma unroll
            for (int c = 0; c < 3; ++c) {
                float a = ldsP[tk][576 + c*48  + h*4  + pp]; sq += a*a;
                float k = ldsP[tk][720 + c*144 + h*12 + pp]; sk += k*k;
            }
        sa_g[(b*H_+h)*N_ + n0 + tk] = c_pt * sq;
        sb_g[(b*H_+h)*N_ + n0 + tk] = c_pt * sk;
    }
}

// ---------------------------------------------------------------------------
// Kernel 2: MFMA flash attention, j-split across wave pairs.
// Block = (bh, 64-row i-tile), 8 waves: rg = w&3 (16-row group),
// jh = w>>2 (jt half). Merge online-softmax states via LDS at the end.
// ---------------------------------------------------------------------------
__global__ __launch_bounds__(512, 2) void attn_kernel(
    const float* __restrict__ Rg, const float* __restrict__ tg,
    const float* __restrict__ maskg, float* __restrict__ ws)
{
    __shared__ u16t smP[8*16*72];     // per-wave P tiles (stride 72)
    __shared__ float mbuf[4*64*20];   // jh=1 state dump
    __shared__ float obuf[64*32];     // point-coords (cols 16..48)

    const u16t* Qb = (const u16t*)(ws + OFF_QB);
    const u16t* Kp = (const u16t*)(ws + OFF_KP);
    const u16t* Vp = (const u16t*)(ws + OFF_VP);
    const float* sa_g = ws + OFF_SA;
    const float* sb_g = ws + OFF_SB;
    u16t* catp = (u16t*)(ws + OFF_CATP);

    const int tid  = threadIdx.x;
    const int w    = tid >> 6, lane = tid & 63;
    const int rg   = w & 3, jh = w >> 2;
    const int kq   = lane >> 4, lx = lane & 15;
    const int bh   = blockIdx.x >> 3;
    const int it   = blockIdx.x & 7;
    const int b    = bh / H_, h = bh % H_;
    const int i0   = it * 64;

    sh8 qfrag = *(const sh8*)(Qb + (bh*N_ + i0 + rg*16 + lx)*32 + kq*8);
    float sa_r[4];
    #pragma unroll
    for (int r = 0; r < 4; ++r)
        sa_r[r] = sa_g[bh*N_ + i0 + rg*16 + kq*4 + r];

    float m_run[4] = {-1e30f,-1e30f,-1e30f,-1e30f};
    float l_run[4] = {0.f,0.f,0.f,0.f};
    f32x4 oc0 = {0.f,0.f,0.f,0.f}, oc1 = oc0, oc2 = oc0;

    const float* mrow = maskg + (size_t)(b*N_ + i0 + rg*16 + kq*4)*N_ + lx;
    u16t* pw = smP + w*1152;

    for (int t = 0; t < 4; ++t) {
        const int jt = jh*4 + t;
        const int j0 = jt * 64;

        f32x4 sc[4];
        #pragma unroll
        for (int st = 0; st < 4; ++st) {
            sh8 kf = *(const sh8*)(Kp + bh*16384 + (jt*4+st)*512 + kq*128 + lx*8);
            f32x4 z = {0.f,0.f,0.f,0.f};
            sc[st] = __builtin_amdgcn_mfma_f32_16x16x32_bf16(qfrag, kf, z, 0, 0, 0);
        }
        float sbv[4];
        #pragma unroll
        for (int st = 0; st < 4; ++st) sbv[st] = sb_g[bh*N_ + j0 + st*16 + lx];
        float mb[16];
        #pragma unroll
        for (int r = 0; r < 4; ++r)
            #pragma unroll
            for (int st = 0; st < 4; ++st)
                mb[r*4+st] = mrow[r*N_ + j0 + st*16];

        float L[16];
        #pragma unroll
        for (int st = 0; st < 4; ++st)
            #pragma unroll
            for (int r = 0; r < 4; ++r)
                L[st*4+r] = sc[st][r] + sa_r[r] + sbv[st] + 1e5f*(mb[r*4+st] - 1.f);

        #pragma unroll
        for (int r = 0; r < 4; ++r) {
            float tm = fmaxf(fmaxf(L[0*4+r], L[1*4+r]), fmaxf(L[2*4+r], L[3*4+r]));
            tm = fmaxf(tm, __shfl_xor(tm, 1));
            tm = fmaxf(tm, __shfl_xor(tm, 2));
            tm = fmaxf(tm, __shfl_xor(tm, 4));
            tm = fmaxf(tm, __shfl_xor(tm, 8));
            float mnew = fmaxf(m_run[r], tm);
            float al = __expf(m_run[r] - mnew);
            m_run[r] = mnew;
            l_run[r] *= al;
            oc0[r] *= al; oc1[r] *= al; oc2[r] *= al;
        }
        #pragma unroll
        for (int st = 0; st < 4; ++st)
            #pragma unroll
            for (int r = 0; r < 4; ++r) {
                float p = __expf(L[st*4+r] - m_run[r]);
                l_run[r] += p;
                pw[(kq*4+r)*72 + st*16 + lx] = f2b(p);
            }
        #pragma unroll
        for (int c = 0; c < 2; ++c) {
            sh8 pa = *(const sh8*)(pw + lx*72 + c*32 + kq*8);
            #pragma unroll
            for (int nq = 0; nq < 3; ++nq) {
                sh8 vf = *(const sh8*)(Vp + bh*24576 + (jt*2+c)*1536 + nq*512
                                        + kq*128 + lx*8);
                if (nq == 0) oc0 = __builtin_amdgcn_mfma_f32_16x16x32_bf16(pa, vf, oc0, 0,0,0);
                if (nq == 1) oc1 = __builtin_amdgcn_mfma_f32_16x16x32_bf16(pa, vf, oc1, 0,0,0);
                if (nq == 2) oc2 = __builtin_amdgcn_mfma_f32_16x16x32_bf16(pa, vf, oc2, 0,0,0);
            }
        }
    }

    // dump jh=1 state
    if (jh == 1) {
        float* mb = mbuf + (rg*64 + lane)*20;
        #pragma unroll
        for (int r = 0; r < 4; ++r) {
            mb[r]      = m_run[r];
            mb[4 + r]  = l_run[r];
            mb[8 + r]  = oc0[r];
            mb[12 + r] = oc1[r];
            mb[16 + r] = oc2[r];
        }
    }
    __syncthreads();
    if (jh == 0) {
        const float* mb = mbuf + (rg*64 + lane)*20;
        float linv[4];
        #pragma unroll
        for (int r = 0; r < 4; ++r) {
            float mB = mb[r];
            float ms = fmaxf(m_run[r], mB);
            float eA = __expf(m_run[r] - ms);
            float eB = __expf(mB - ms);
            float l = l_run[r]*eA + mb[4+r]*eB;
            oc0[r] = oc0[r]*eA + mb[8+r]*eB;
            oc1[r] = oc1[r]*eA + mb[12+r]*eB;
            oc2[r] = oc2[r]*eA + mb[16+r]*eB;
            l += __shfl_xor(l, 1); l += __shfl_xor(l, 2);
            l += __shfl_xor(l, 4); l += __shfl_xor(l, 8);
            linv[r] = 1.f / l;
        }

        // o part -> CAT-packed (bf16), points -> obuf
        #pragma unroll
        for (int r = 0; r < 4; ++r) {
            int tok = b*N_ + i0 + rg*16 + kq*4 + r;
            catp[catp_idx(tok, h*16 + lx)] = f2b(oc0[r] * linv[r]);
            obuf[(rg*16 + kq*4 + r)*32 + lx]      = oc1[r] * linv[r];
            obuf[(rg*16 + kq*4 + r)*32 + 16 + lx] = oc2[r] * linv[r];
        }

        // points: R^T g - t, norm; wave handles its own 16 rows x 8 pts
        #pragma unroll
        for (int tsk = 0; tsk < 2; ++tsk) {
            int task = lane + tsk*64;
            int r = task >> 3, pv = task & 7;
            int tok = b*N_ + i0 + rg*16 + r;
            const float* Rr = Rg + tok*9;
            const float* tr = tg + tok*3;
            float g0 = obuf[(rg*16 + r)*32 + pv*3 + 0];
            float g1 = obuf[(rg*16 + r)*32 + pv*3 + 1];
            float g2 = obuf[(rg*16 + r)*32 + pv*3 + 2];
            float px = Rr[0]*g0 + Rr[3]*g1 + Rr[6]*g2 - tr[0];
            float py = Rr[1]*g0 + Rr[4]*g1 + Rr[7]*g2 - tr[1];
            float pz = Rr[2]*g0 + Rr[5]*g1 + Rr[8]*g2 - tr[2];
            float nrm = sqrtf(px*px + py*py + pz*pz + 1e-8f);
            catp[catp_idx(tok, 192 + h*8 + pv)] = f2b(px);
            catp[catp_idx(tok, 288 + h*8 + pv)] = f2b(py);
            catp[catp_idx(tok, 384 + h*8 + pv)] = f2b(pz);
            catp[catp_idx(tok, 480 + h*8 + pv)] = f2b(nrm);
        }
    }
}

// ---------------------------------------------------------------------------
// Kernel 3: out GEMM, no LDS. grid (2 nt, 64 mt) x 256. Wave w: cols
// nt*64+w*16..+16, rows mt*16..+16. K=576: 18 ksteps x 1 MFMA.
// ---------------------------------------------------------------------------
__global__ __launch_bounds__(256) void out_kernel(
    const float* __restrict__ bout, const float* __restrict__ ws,
    float* __restrict__ out)
{
    const int tid = threadIdx.x;
    const int w = tid >> 6, lane = tid & 63;
    const int lx = lane & 15, kq = lane >> 4;
    const int nt = blockIdx.x, mt = blockIdx.y;

    const sh8* Ap = (const sh8*)((const u16t*)(ws + OFF_CATP));
    const sh8* Bp = (const sh8*)((const u16t*)(ws + OFF_WOP));

    f32x4 acc = {0.f,0.f,0.f,0.f};
    for (int ks = 0; ks < 18; ++ks) {
        sh8 af = Ap[((mt*18 + ks)*4 + kq)*16 + lx];
        sh8 bf = Bp[((nt*18 + ks)*4 + kq)*64 + w*16 + lx];
        acc = __builtin_amdgcn_mfma_f32_16x16x32_bf16(af, bf, acc, 0, 0, 0);
    }
    int col = nt*64 + w*16 + lx;
    float bv = bout[col];
    #pragma unroll
    for (int r = 0; r < 4; ++r) {
        int row = mt*16 + kq*4 + r;
        out[row*128 + col] = acc[r] + bv;
    }
}

extern "C" void kernel_launch(void* const* d_in, const int* in_sizes, int n_in,
                              void* d_out, int out_size, void* d_ws, size_t ws_size,
                              hipStream_t stream) {
    const float* s    = (const float*)d_in[0];
    const float* R    = (const float*)d_in[1];
    const float* t    = (const float*)d_in[2];
    const float* mask = (const float*)d_in[3];
    const float* Wq   = (const float*)d_in[4];
    const float* bq   = (const float*)d_in[5];
    const float* Wkv  = (const float*)d_in[6];
    const float* bkv  = (const float*)d_in[7];
    const float* Wqp  = (const float*)d_in[8];
    const float* bqp  = (const float*)d_in[9];
    const float* Wkvp = (const float*)d_in[10];
    const float* bkvp = (const float*)d_in[11];
    const float* hw   = (const float*)d_in[12];
    const float* Wout = (const float*)d_in[13];
    const float* bout = (const float*)d_in[14];
    float* ws  = (float*)d_ws;
    float* out = (float*)d_out;

    convert_kernel<<<113, 256, 0, stream>>>(Wq, bq, Wkv, bkv,
                                            Wqp, bqp, Wkvp, bkvp, Wout, ws);
    projpack_kernel<<<64, 256, 0, stream>>>(s, R, t, hw, ws);
    attn_kernel<<<BH_*8, 512, 0, stream>>>(R, t, mask, ws);
    out_kernel<<<dim3(2, 64), 256, 0, stream>>>(bout, ws, out);
}

// Round 7
// 111.502 us; speedup vs baseline: 1.0327x; 1.0327x over previous
//
#include <hip/hip_runtime.h>
#include <hip/hip_bf16.h>
#include <math.h>

#define H_    12
#define B_    2
#define N_    512
#define BH_   (B_*H_)
#define QSCALE 0.14433756729740643f          // 1/sqrt(48)
#define CPT_K  0.13608276348795434f          // sqrt(1/54)

// ---------------- ws layout (float units) ----------------
#define OFF_WPP  1245184                     // bf16 Wproj-pack [18nt][4ks][4kq][64n][8]
#define OFF_WOP  1318912                     // bf16 Wout-pack  [2nt][18ks][4kq][64n][8]
#define OFF_BIA  1355776                     // f32 fused bias [1152]
#define OFF_QB   1356928                     // bf16 [bh][512][32]
#define OFF_KP   1553536                     // bf16 [bh][32jt][4kq][16j][8]
#define OFF_VP   1750144                     // bf16 [bh][16jt32][3nq][4kq][16n][8j]
#define OFF_SA   2045056                     // f32 [bh*512]
#define OFF_SB   2057344                     // f32 [bh*512]
#define OFF_CATP 2069632                     // bf16 [64mt][18ks][4kq][16m][8]

typedef __attribute__((ext_vector_type(8))) short sh8;
typedef __attribute__((ext_vector_type(4))) float f32x4;
typedef unsigned short u16t;

static __device__ __forceinline__ u16t f2b(float x) {
    __hip_bfloat16 h = __float2bfloat16(x);
    return *reinterpret_cast<u16t*>(&h);
}
static __device__ __forceinline__ int catp_idx(int tok, int col) {
    return (tok >> 4)*9216 + (col >> 5)*512 + ((col >> 3) & 3)*128
         + (tok & 15)*8 + (col & 7);
}

// ---------------------------------------------------------------------------
// Kernel 0: pack Wproj, Wout into MFMA-fragment bf16 images + fused bias.
// sh8 task ranges: [0,18432) Wproj, [18432,27648) Wout, [27648,28800) bias.
// ---------------------------------------------------------------------------
__global__ __launch_bounds__(256) void convert_kernel(
    const float* __restrict__ Wq,  const float* __restrict__ bq,
    const float* __restrict__ Wkv, const float* __restrict__ bkv,
    const float* __restrict__ Wqp, const float* __restrict__ bqp,
    const float* __restrict__ Wkvp,const float* __restrict__ bkvp,
    const float* __restrict__ Wout, float* __restrict__ ws)
{
    const int g = blockIdx.x * 256 + threadIdx.x;
    union { sh8 v; u16t u[8]; } pk;

    if (g < 18432) {                       // Wproj-packed
        int u = g;
        int n = u & 63, kq = (u >> 6) & 3, ks = (u >> 8) & 3, nt = u >> 10;
        int col = nt*64 + n, k0 = ks*32 + kq*8;
        const float* w; int lc, od;
        if (col < 192)      { w = Wq;   lc = col;     od = 192; }
        else if (col < 576) { w = Wkv;  lc = col-192; od = 384; }
        else if (col < 720) { w = Wqp;  lc = col-576; od = 144; }
        else                { w = Wkvp; lc = col-720; od = 432; }
        #pragma unroll
        for (int j = 0; j < 8; ++j) pk.u[j] = f2b(w[(k0+j)*od + lc]);
        *((sh8*)((u16t*)(ws + OFF_WPP)) + u) = pk.v;
    } else if (g < 27648) {                // Wout-packed (9216 frags)
        int u = g - 18432;
        int n = u & 63, kq = (u >> 6) & 3, rem = u >> 8;   // rem in [0,36)
        int ks = rem % 18, nt = rem / 18;
        int col = nt*64 + n, k0 = ks*32 + kq*8;
        #pragma unroll
        for (int j = 0; j < 8; ++j) pk.u[j] = f2b(Wout[(k0+j)*128 + col]);
        *((sh8*)((u16t*)(ws + OFF_WOP)) + u) = pk.v;
    } else if (g < 28800) {                // fused bias
        int col = g - 27648;
        float bv;
        if (col < 192)      bv = bq[col];
        else if (col < 576) bv = bkv[col-192];
        else if (col < 720) bv = bqp[col-576];
        else                bv = bkvp[col-720];
        ws[OFF_BIA + col] = bv;
    }
}

// ---------------------------------------------------------------------------
// Kernel 1: fused proj GEMM + rotation + bf16 pack. Block = 8 tokens,
// 8 waves; wave w computes col-groups [w*9, w*9+9). A-frag rows lx&7
// (rows 8-15 are discarded duplicates; stores predicated kq<2).
// ---------------------------------------------------------------------------
__global__ __launch_bounds__(512) void projpack_kernel(
    const float* __restrict__ s,
    const float* __restrict__ Rg, const float* __restrict__ tg,
    const float* __restrict__ hwg, float* __restrict__ ws)
{
    __shared__ float ldsP[8][1160];   // 8 tokens x 1152 (+8 pad)

    u16t* Qb = (u16t*)(ws + OFF_QB);
    u16t* Kp = (u16t*)(ws + OFF_KP);
    u16t* Vp = (u16t*)(ws + OFF_VP);
    float* sa_g = ws + OFF_SA;
    float* sb_g = ws + OFF_SB;

    const int tid  = threadIdx.x;
    const int w    = tid >> 6, lane = tid & 63;
    const int kq   = lane >> 4, lx = lane & 15;
    const int tok0 = blockIdx.x * 8;
    const int b    = tok0 >> 9, n0 = tok0 & 511;

    // A-frags: s rows tok0 + (lx&7), k = ks*32 + kq*8 .. +8
    sh8 afr[4];
    #pragma unroll
    for (int ks = 0; ks < 4; ++ks) {
        const float* src = s + (tok0 + (lx & 7))*128 + ks*32 + kq*8;
        float4 u0 = *(const float4*)(src);
        float4 u1 = *(const float4*)(src+4);
        union { sh8 v; u16t u[8]; } pk;
        pk.u[0]=f2b(u0.x); pk.u[1]=f2b(u0.y); pk.u[2]=f2b(u0.z); pk.u[3]=f2b(u0.w);
        pk.u[4]=f2b(u1.x); pk.u[5]=f2b(u1.y); pk.u[6]=f2b(u1.z); pk.u[7]=f2b(u1.w);
        afr[ks] = pk.v;
    }

    const sh8* Bp = (const sh8*)((const u16t*)(ws + OFF_WPP));
    const float* bias = ws + OFF_BIA;

    #pragma unroll 3
    for (int g = 0; g < 9; ++g) {
        int gg = w*9 + g;                  // col-group 0..71
        int nt = gg >> 2, nq = gg & 3;
        f32x4 acc = {0.f,0.f,0.f,0.f};
        #pragma unroll
        for (int ks = 0; ks < 4; ++ks) {
            sh8 bf = Bp[((nt*4 + ks)*4 + kq)*64 + nq*16 + lx];
            acc = __builtin_amdgcn_mfma_f32_16x16x32_bf16(afr[ks], bf, acc, 0, 0, 0);
        }
        float bv = bias[gg*16 + lx];
        if (kq < 2) {                      // C rows 0..7 only
            #pragma unroll
            for (int r = 0; r < 4; ++r)
                ldsP[kq*4 + r][gg*16 + lx] = acc[r] + bv;
        }
    }
    __syncthreads();

    // in-place rotation: qp (cols 576..720, x/y/z at p, 48+p, 96+p)
    for (int idx = tid; idx < 8*48; idx += 512) {
        int tk = idx / 48, p = idx % 48;
        int tok = tok0 + tk;
        const float* Rr = Rg + tok*9;
        const float* tr = tg + tok*3;
        float x0 = ldsP[tk][576 +  0 + p];
        float x1 = ldsP[tk][576 + 48 + p];
        float x2 = ldsP[tk][576 + 96 + p];
        ldsP[tk][576 +  0 + p] = Rr[0]*x0 + Rr[1]*x1 + Rr[2]*x2 + tr[0];
        ldsP[tk][576 + 48 + p] = Rr[3]*x0 + Rr[4]*x1 + Rr[5]*x2 + tr[1];
        ldsP[tk][576 + 96 + p] = Rr[6]*x0 + Rr[7]*x1 + Rr[8]*x2 + tr[2];
    }
    // in-place rotation: kvp (cols 720..1152, x/y/z at p, 144+p, 288+p)
    for (int idx = tid; idx < 8*144; idx += 512) {
        int tk = idx / 144, p = idx % 144;
        int tok = tok0 + tk;
        const float* Rr = Rg + tok*9;
        const float* tr = tg + tok*3;
        float x0 = ldsP[tk][720 +   0 + p];
        float x1 = ldsP[tk][720 + 144 + p];
        float x2 = ldsP[tk][720 + 288 + p];
        ldsP[tk][720 +   0 + p] = Rr[0]*x0 + Rr[1]*x1 + Rr[2]*x2 + tr[0];
        ldsP[tk][720 + 144 + p] = Rr[3]*x0 + Rr[4]*x1 + Rr[5]*x2 + tr[1];
        ldsP[tk][720 + 288 + p] = Rr[6]*x0 + Rr[7]*x1 + Rr[8]*x2 + tr[2];
    }
    __syncthreads();

    // Qb rows : tasks (tk,h,half)
    for (int idx = tid; idx < 8*24; idx += 512) {
        int tk = idx / 24, r2 = idx % 24, h = r2 >> 1, half = r2 & 1;
        float hx = hwg[h];
        float sp = (hx > 20.f) ? hx : log1pf(__expf(hx));
        float c_pt = -0.5f * sp * CPT_K;
        union { sh8 v[2]; u16t u[16]; } pk;
        if (half == 0) {
            #pragma unroll
            for (int e = 0; e < 16; ++e) pk.u[e] = f2b(ldsP[tk][h*16 + e] * QSCALE);
        } else {
            float qs = -2.f * c_pt;
            #pragma unroll
            for (int e = 0; e < 12; ++e)
                pk.u[e] = f2b(ldsP[tk][576 + (e%3)*48 + h*4 + e/3] * qs);
            pk.u[12]=0; pk.u[13]=0; pk.u[14]=0; pk.u[15]=0;
        }
        u16t* dst = Qb + ((b*H_+h)*N_ + n0 + tk)*32 + half*16;
        *(sh8*)dst = pk.v[0];
        *(sh8*)(dst+8) = pk.v[1];
    }
    // Kp: frag-packed [bh][jt16][kq][j16][8] : tasks (tk,h,fq)
    for (int idx = tid; idx < 8*48; idx += 512) {
        int tk = idx / 48, r2 = idx % 48, h = r2 >> 2, fq = r2 & 3;
        int j = n0 + tk, bh = b*H_ + h;
        union { sh8 v; u16t u[8]; } pk;
        #pragma unroll
        for (int e = 0; e < 8; ++e) {
            int c = fq*8 + e;
            float val;
            if (c < 16)      val = ldsP[tk][192 + h*32 + c];
            else if (c < 28) val = ldsP[tk][720 + ((c-16)%3)*144 + h*12 + (c-16)/3];
            else             val = 0.f;
            pk.u[e] = f2b(val);
        }
        *(sh8*)(Kp + bh*16384 + (j>>4)*512 + fq*128 + (j&15)*8) = pk.v;
    }
    // Vp: frag-packed, 16B stores along j (8 tokens = one sh8): tasks (h,d)
    for (int idx = tid; idx < 480; idx += 512) {
        int h = idx / 40, d = idx % 40;
        int bh = b*H_ + h;
        union { sh8 v; u16t u[8]; } pk;
        #pragma unroll
        for (int e = 0; e < 8; ++e) {
            float val;
            if (d < 16) val = ldsP[e][192 + h*32 + 16 + d];
            else        val = ldsP[e][720 + ((d-16)%3)*144 + h*12 + 4 + (d-16)/3];
            pk.u[e] = f2b(val);
        }
        int j = n0;
        *(sh8*)(Vp + bh*24576 + (j>>5)*1536 + (d>>4)*512 + ((j>>3)&3)*128
                + (d&15)*8) = pk.v;
    }
    // sa/sb : tasks (tk,h)
    for (int idx = tid; idx < 8*12; idx += 512) {
        int tk = idx / 12, h = idx % 12;
        float hx = hwg[h];
        float sp = (hx > 20.f) ? hx : log1pf(__expf(hx));
        float c_pt = -0.5f * sp * CPT_K;
        float sq = 0.f, sk = 0.f;
        #pragma unroll
        for (int pp = 0; pp < 4; ++pp)
            #pragma unroll
            for (int c = 0; c < 3; ++c) {
                float a = ldsP[tk][576 + c*48  + h*4  + pp]; sq += a*a;
                float k = ldsP[tk][720 + c*144 + h*12 + pp]; sk += k*k;
            }
        sa_g[(b*H_+h)*N_ + n0 + tk] = c_pt * sq;
        sb_g[(b*H_+h)*N_ + n0 + tk] = c_pt * sk;
    }
}

// ---------------------------------------------------------------------------
// Kernel 2: MFMA flash attention, j-split across wave pairs.
// Block = (bh, 64-row i-tile), 8 waves: rg = w&3 (16-row group),
// jh = w>>2 (jt half). Merge online-softmax states via LDS at the end.
// ---------------------------------------------------------------------------
__global__ __launch_bounds__(512, 2) void attn_kernel(
    const float* __restrict__ Rg, const float* __restrict__ tg,
    const float* __restrict__ maskg, float* __restrict__ ws)
{
    __shared__ u16t smP[8*16*72];     // per-wave P tiles (stride 72)
    __shared__ float mbuf[4*64*20];   // jh=1 state dump
    __shared__ float obuf[64*32];     // point-coords (cols 16..48)

    const u16t* Qb = (const u16t*)(ws + OFF_QB);
    const u16t* Kp = (const u16t*)(ws + OFF_KP);
    const u16t* Vp = (const u16t*)(ws + OFF_VP);
    const float* sa_g = ws + OFF_SA;
    const float* sb_g = ws + OFF_SB;
    u16t* catp = (u16t*)(ws + OFF_CATP);

    const int tid  = threadIdx.x;
    const int w    = tid >> 6, lane = tid & 63;
    const int rg   = w & 3, jh = w >> 2;
    const int kq   = lane >> 4, lx = lane & 15;
    const int bh   = blockIdx.x >> 3;
    const int it   = blockIdx.x & 7;
    const int b    = bh / H_, h = bh % H_;
    const int i0   = it * 64;

    sh8 qfrag = *(const sh8*)(Qb + (bh*N_ + i0 + rg*16 + lx)*32 + kq*8);
    float sa_r[4];
    #pragma unroll
    for (int r = 0; r < 4; ++r)
        sa_r[r] = sa_g[bh*N_ + i0 + rg*16 + kq*4 + r];

    float m_run[4] = {-1e30f,-1e30f,-1e30f,-1e30f};
    float l_run[4] = {0.f,0.f,0.f,0.f};
    f32x4 oc0 = {0.f,0.f,0.f,0.f}, oc1 = oc0, oc2 = oc0;

    const float* mrow = maskg + (size_t)(b*N_ + i0 + rg*16 + kq*4)*N_ + lx;
    u16t* pw = smP + w*1152;

    for (int t = 0; t < 4; ++t) {
        const int jt = jh*4 + t;
        const int j0 = jt * 64;

        f32x4 sc[4];
        #pragma unroll
        for (int st = 0; st < 4; ++st) {
            sh8 kf = *(const sh8*)(Kp + bh*16384 + (jt*4+st)*512 + kq*128 + lx*8);
            f32x4 z = {0.f,0.f,0.f,0.f};
            sc[st] = __builtin_amdgcn_mfma_f32_16x16x32_bf16(qfrag, kf, z, 0, 0, 0);
        }
        float sbv[4];
        #pragma unroll
        for (int st = 0; st < 4; ++st) sbv[st] = sb_g[bh*N_ + j0 + st*16 + lx];
        float mb[16];
        #pragma unroll
        for (int r = 0; r < 4; ++r)
            #pragma unroll
            for (int st = 0; st < 4; ++st)
                mb[r*4+st] = mrow[r*N_ + j0 + st*16];

        float L[16];
        #pragma unroll
        for (int st = 0; st < 4; ++st)
            #pragma unroll
            for (int r = 0; r < 4; ++r)
                L[st*4+r] = sc[st][r] + sa_r[r] + sbv[st] + 1e5f*(mb[r*4+st] - 1.f);

        #pragma unroll
        for (int r = 0; r < 4; ++r) {
            float tm = fmaxf(fmaxf(L[0*4+r], L[1*4+r]), fmaxf(L[2*4+r], L[3*4+r]));
            tm = fmaxf(tm, __shfl_xor(tm, 1));
            tm = fmaxf(tm, __shfl_xor(tm, 2));
            tm = fmaxf(tm, __shfl_xor(tm, 4));
            tm = fmaxf(tm, __shfl_xor(tm, 8));
            float mnew = fmaxf(m_run[r], tm);
            float al = __expf(m_run[r] - mnew);
            m_run[r] = mnew;
            l_run[r] *= al;
            oc0[r] *= al; oc1[r] *= al; oc2[r] *= al;
        }
        #pragma unroll
        for (int st = 0; st < 4; ++st)
            #pragma unroll
            for (int r = 0; r < 4; ++r) {
                float p = __expf(L[st*4+r] - m_run[r]);
                l_run[r] += p;
                pw[(kq*4+r)*72 + st*16 + lx] = f2b(p);
            }
        #pragma unroll
        for (int c = 0; c < 2; ++c) {
            sh8 pa = *(const sh8*)(pw + lx*72 + c*32 + kq*8);
            #pragma unroll
            for (int nq = 0; nq < 3; ++nq) {
                sh8 vf = *(const sh8*)(Vp + bh*24576 + (jt*2+c)*1536 + nq*512
                                        + kq*128 + lx*8);
                if (nq == 0) oc0 = __builtin_amdgcn_mfma_f32_16x16x32_bf16(pa, vf, oc0, 0,0,0);
                if (nq == 1) oc1 = __builtin_amdgcn_mfma_f32_16x16x32_bf16(pa, vf, oc1, 0,0,0);
                if (nq == 2) oc2 = __builtin_amdgcn_mfma_f32_16x16x32_bf16(pa, vf, oc2, 0,0,0);
            }
        }
    }

    // dump jh=1 state
    if (jh == 1) {
        float* mb = mbuf + (rg*64 + lane)*20;
        #pragma unroll
        for (int r = 0; r < 4; ++r) {
            mb[r]      = m_run[r];
            mb[4 + r]  = l_run[r];
            mb[8 + r]  = oc0[r];
            mb[12 + r] = oc1[r];
            mb[16 + r] = oc2[r];
        }
    }
    __syncthreads();
    if (jh == 0) {
        const float* mb = mbuf + (rg*64 + lane)*20;
        float linv[4];
        #pragma unroll
        for (int r = 0; r < 4; ++r) {
            float mB = mb[r];
            float ms = fmaxf(m_run[r], mB);
            float eA = __expf(m_run[r] - ms);
            float eB = __expf(mB - ms);
            float l = l_run[r]*eA + mb[4+r]*eB;
            oc0[r] = oc0[r]*eA + mb[8+r]*eB;
            oc1[r] = oc1[r]*eA + mb[12+r]*eB;
            oc2[r] = oc2[r]*eA + mb[16+r]*eB;
            l += __shfl_xor(l, 1); l += __shfl_xor(l, 2);
            l += __shfl_xor(l, 4); l += __shfl_xor(l, 8);
            linv[r] = 1.f / l;
        }

        // o part -> CAT-packed (bf16), points -> obuf
        #pragma unroll
        for (int r = 0; r < 4; ++r) {
            int tok = b*N_ + i0 + rg*16 + kq*4 + r;
            catp[catp_idx(tok, h*16 + lx)] = f2b(oc0[r] * linv[r]);
            obuf[(rg*16 + kq*4 + r)*32 + lx]      = oc1[r] * linv[r];
            obuf[(rg*16 + kq*4 + r)*32 + 16 + lx] = oc2[r] * linv[r];
        }

        // points: R^T g - t, norm; wave handles its own 16 rows x 8 pts
        #pragma unroll
        for (int tsk = 0; tsk < 2; ++tsk) {
            int task = lane + tsk*64;
            int r = task >> 3, pv = task & 7;
            int tok = b*N_ + i0 + rg*16 + r;
            const float* Rr = Rg + tok*9;
            const float* tr = tg + tok*3;
            float g0 = obuf[(rg*16 + r)*32 + pv*3 + 0];
            float g1 = obuf[(rg*16 + r)*32 + pv*3 + 1];
            float g2 = obuf[(rg*16 + r)*32 + pv*3 + 2];
            float px = Rr[0]*g0 + Rr[3]*g1 + Rr[6]*g2 - tr[0];
            float py = Rr[1]*g0 + Rr[4]*g1 + Rr[7]*g2 - tr[1];
            float pz = Rr[2]*g0 + Rr[5]*g1 + Rr[8]*g2 - tr[2];
            float nrm = sqrtf(px*px + py*py + pz*pz + 1e-8f);
            catp[catp_idx(tok, 192 + h*8 + pv)] = f2b(px);
            catp[catp_idx(tok, 288 + h*8 + pv)] = f2b(py);
            catp[catp_idx(tok, 384 + h*8 + pv)] = f2b(pz);
            catp[catp_idx(tok, 480 + h*8 + pv)] = f2b(nrm);
        }
    }
}

// ---------------------------------------------------------------------------
// Kernel 3: out GEMM, split-K across wave pairs. grid (2 nt, 64 mt) x 512.
// Wave (cg = w&3, kh = w>>2): cols nt*64+cg*16, ks range kh*9..+9.
// kh=1 partials merged via LDS.
// ---------------------------------------------------------------------------
__global__ __launch_bounds__(512) void out_kernel(
    const float* __restrict__ bout, const float* __restrict__ ws,
    float* __restrict__ out)
{
    __shared__ float part[4][64][4];

    const int tid = threadIdx.x;
    const int w = tid >> 6, lane = tid & 63;
    const int cg = w & 3, kh = w >> 2;
    const int lx = lane & 15, kq = lane >> 4;
    const int nt = blockIdx.x, mt = blockIdx.y;

    const sh8* Ap = (const sh8*)((const u16t*)(ws + OFF_CATP));
    const sh8* Bp = (const sh8*)((const u16t*)(ws + OFF_WOP));

    f32x4 acc = {0.f,0.f,0.f,0.f};
    #pragma unroll 3
    for (int i = 0; i < 9; ++i) {
        int ks = kh*9 + i;
        sh8 af = Ap[((mt*18 + ks)*4 + kq)*16 + lx];
        sh8 bf = Bp[((nt*18 + ks)*4 + kq)*64 + cg*16 + lx];
        acc = __builtin_amdgcn_mfma_f32_16x16x32_bf16(af, bf, acc, 0, 0, 0);
    }
    if (kh == 1) {
        #pragma unroll
        for (int r = 0; r < 4; ++r) part[cg][lane][r] = acc[r];
    }
    __syncthreads();
    if (kh == 0) {
        int col = nt*64 + cg*16 + lx;
        float bv = bout[col];
        #pragma unroll
        for (int r = 0; r < 4; ++r) {
            int row = mt*16 + kq*4 + r;
            out[row*128 + col] = acc[r] + part[cg][lane][r] + bv;
        }
    }
}

extern "C" void kernel_launch(void* const* d_in, const int* in_sizes, int n_in,
                              void* d_out, int out_size, void* d_ws, size_t ws_size,
                              hipStream_t stream) {
    const float* s    = (const float*)d_in[0];
    const float* R    = (const float*)d_in[1];
    const float* t    = (const float*)d_in[2];
    const float* mask = (const float*)d_in[3];
    const float* Wq   = (const float*)d_in[4];
    const float* bq   = (const float*)d_in[5];
    const float* Wkv  = (const float*)d_in[6];
    const float* bkv  = (const float*)d_in[7];
    const float* Wqp  = (const float*)d_in[8];
    const float* bqp  = (const float*)d_in[9];
    const float* Wkvp = (const float*)d_in[10];
    const float* bkvp = (const float*)d_in[11];
    const float* hw   = (const float*)d_in[12];
    const float* Wout = (const float*)d_in[13];
    const float* bout = (const float*)d_in[14];
    float* ws  = (float*)d_ws;
    float* out = (float*)d_out;

    convert_kernel<<<113, 256, 0, stream>>>(Wq, bq, Wkv, bkv,
                                            Wqp, bqp, Wkvp, bkvp, Wout, ws);
    projpack_kernel<<<128, 512, 0, stream>>>(s, R, t, hw, ws);
    attn_kernel<<<BH_*8, 512, 0, stream>>>(R, t, mask, ws);
    out_kernel<<<dim3(2, 64), 512, 0, stream>>>(bout, ws, out);
}